// Round 1
// baseline (4352.611 us; speedup 1.0000x reference)
//
#include <hip/hip_runtime.h>

#define B_    64
#define T_    1024
#define H_    1024
#define HALF_ 512
#define NWG_SCAN 128
#define HBUF_HALF 131072   // shorts per double-buffer half: 2*64*1024
#define LOCAL_ROUNDS 8     // stale local polls before escalating to device-scope buffer

typedef short bf16x8 __attribute__((ext_vector_type(8)));
typedef short bf16x4 __attribute__((ext_vector_type(4)));
typedef _Float16 f16x8 __attribute__((ext_vector_type(8)));
typedef float f32x4  __attribute__((ext_vector_type(4)));
typedef unsigned int u32x4 __attribute__((ext_vector_type(4)));

__device__ __forceinline__ short f2bf(float f) {
    unsigned u = __builtin_bit_cast(unsigned, f);
    u += 0x7fffu + ((u >> 16) & 1u);
    return (short)(u >> 16);
}

__device__ __forceinline__ short f2h(float f) {
    return (short)__builtin_bit_cast(unsigned short, (_Float16)f);
}

__device__ __forceinline__ float tanh_fast(float x) {
    return 1.0f - 2.0f / (__expf(2.0f * x) + 1.0f);
}

// ---------------- Phase 1: gi = bf16(x) @ bf16(W_ih)^T + (b_ih + b_hh) --------
__global__ __launch_bounds__(256) void gi_gemm(
        const float* __restrict__ X, const float* __restrict__ Wih,
        const float* __restrict__ bih, const float* __restrict__ bhh,
        float* __restrict__ out) {
    __shared__ short As[128][40];
    __shared__ short Bs[128][40];
    const int bid = blockIdx.x;
    const int tn = bid & 7;
    const int tm = bid >> 3;
    const int tid = threadIdx.x;
    const int l  = tid & 63;
    const int w  = tid >> 6;
    const int wr = w >> 1, wc = w & 1;
    const int lc = l & 15,  lr = l >> 4;

    const float* Ab = X   + (size_t)tm * 128 * 1024;
    const float* Bb = Wih + (size_t)tn * 128 * 1024;
    const int srow = tid >> 3;
    const int sc4  = (tid & 7) * 4;

    f32x4 acc[4][4];
#pragma unroll
    for (int m = 0; m < 4; m++)
#pragma unroll
        for (int n = 0; n < 4; n++) acc[m][n] = (f32x4){0.f, 0.f, 0.f, 0.f};

    f32x4 ra[4], rb[4];
#pragma unroll
    for (int c = 0; c < 4; c++) {
        ra[c] = *reinterpret_cast<const f32x4*>(Ab + (size_t)(srow + 32*c) * 1024 + sc4);
        rb[c] = *reinterpret_cast<const f32x4*>(Bb + (size_t)(srow + 32*c) * 1024 + sc4);
    }

    for (int k0 = 0; k0 < 1024; k0 += 32) {
        __syncthreads();
#pragma unroll
        for (int c = 0; c < 4; c++) {
            bf16x4 va = { f2bf(ra[c].x), f2bf(ra[c].y), f2bf(ra[c].z), f2bf(ra[c].w) };
            bf16x4 vb = { f2bf(rb[c].x), f2bf(rb[c].y), f2bf(rb[c].z), f2bf(rb[c].w) };
            *reinterpret_cast<bf16x4*>(&As[srow + 32*c][sc4]) = va;
            *reinterpret_cast<bf16x4*>(&Bs[srow + 32*c][sc4]) = vb;
        }
        __syncthreads();
        if (k0 + 32 < 1024) {
            const float* Ak = Ab + k0 + 32;
            const float* Bk = Bb + k0 + 32;
#pragma unroll
            for (int c = 0; c < 4; c++) {
                ra[c] = *reinterpret_cast<const f32x4*>(Ak + (size_t)(srow + 32*c) * 1024 + sc4);
                rb[c] = *reinterpret_cast<const f32x4*>(Bk + (size_t)(srow + 32*c) * 1024 + sc4);
            }
        }
        bf16x8 af[4], bfr[4];
#pragma unroll
        for (int m = 0; m < 4; m++)
            af[m] = *reinterpret_cast<bf16x8*>(&As[wr*64 + m*16 + lc][lr*8]);
#pragma unroll
        for (int n = 0; n < 4; n++)
            bfr[n] = *reinterpret_cast<bf16x8*>(&Bs[wc*64 + n*16 + lc][lr*8]);
#pragma unroll
        for (int m = 0; m < 4; m++)
#pragma unroll
            for (int n = 0; n < 4; n++)
                acc[m][n] = __builtin_amdgcn_mfma_f32_16x16x32_bf16(af[m], bfr[n], acc[m][n], 0, 0, 0);
    }

#pragma unroll
    for (int n = 0; n < 4; n++) {
        const int col = tn*128 + wc*64 + n*16 + lc;
        const float bs = bih[col] + bhh[col];
#pragma unroll
        for (int m = 0; m < 4; m++) {
            const int row0 = tm*128 + wr*64 + m*16 + lr*4;
#pragma unroll
            for (int j = 0; j < 4; j++)
                out[(size_t)(row0 + j) * 1024 + col] = acc[m][n][j] + bs;
        }
    }
}

// ---------------- Phase 2: batch-partitioned barrier-free scan ---------------
// WG decode remapped so each communication group (parity, batch-group) = the
// 16 WGs with blockIdx % 8 == group id. Under round-robin dispatch these
// co-reside on ONE XCD and share its L2 -> h exchanged at L2 scope (sc0
// store/load, ~200cy) instead of device scope (~900cy). Correctness does NOT
// depend on placement: producers dual-store (sc0 local buffer + sc0 sc1
// device-scope fallback buffer); consumers poll local, and any slot still
// stale after LOCAL_ROUNDS escalates to device-scope polls of the fallback,
// which is guaranteed visible. Epoch-LSB protocol unchanged (epoch = step%3+1,
// 0 invalid; both buffers zeroed per launch; dispatch-boundary L2 invalidation
// kills cross-replay stale lines).
__global__ __launch_bounds__(256, 1) void rnn_scan(
        const float* __restrict__ Whh, float* __restrict__ out,
        short* __restrict__ hloc, short* __restrict__ hrem) {
    __shared__ short hB[16 * 1024];   // h stage [16 batch][1024 k], swizzled
    __shared__ short htr[16 * 68];    // output transpose [batch][col+pad]
    const int wg = blockIdx.x;
    const int p  = (wg >> 2) & 1;     // parity        (group id = wg & 7)
    const int g  = wg & 3;            // batch group (16 batches)
    const int s  = wg >> 3;           // col slice (64 cols)
    const int tid = threadIdx.x;
    const int l  = tid & 63;
    const int w  = tid >> 6;
    const int lc = l & 15, lr = l >> 4;
    const int sb = tid >> 4;          // staging batch row 0..15
    const int sg = tid & 15;          // staging granule index

    // W_hh rows [s*64 + w*16 + lc], fp32 -> fp16, direct to 128 VGPRs
    bf16x8 breg[32];
    {
        const float* wrow = Whh + (size_t)(s*64 + w*16 + lc) * 1024;
#pragma unroll
        for (int kc = 0; kc < 32; kc++) {
            f32x4 v0 = *reinterpret_cast<const f32x4*>(wrow + kc*32 + lr*8);
            f32x4 v1 = *reinterpret_cast<const f32x4*>(wrow + kc*32 + lr*8 + 4);
            bf16x8 q = { f2h(v0.x), f2h(v0.y), f2h(v0.z), f2h(v0.w),
                         f2h(v1.x), f2h(v1.y), f2h(v1.z), f2h(v1.w) };
            breg[kc] = q;
        }
    }

    const unsigned hload_base = (unsigned)((p*64 + g*16 + sb) * 1024 + sg*8);
    const unsigned hstore_off = (unsigned)((p*64 + g*16 + sb) * 1024 + s*64 + sg*4);
    const int col = s*64 + w*16 + lc;

    for (int step = 0; step < HALF_; step++) {
        const int tt = (p == 0) ? (2*step) : (step == 0 ? T_-1 : 2*step - 1);
        const int epw = step % 3 + 1;
        const int epv = (step + 2) % 3 + 1;   // prev step's epw
        f32x4 acc = (f32x4){0.f, 0.f, 0.f, 0.f};
        float gi[4]; unsigned ob[4];

        if (step) {
            // 8 x 16B loads of this group's h (contiguous 32 KB per WG),
            // L2-scope from the local buffer (same-XCD producers' sc0 stores)
            bf16x8 hl[8];
            const size_t hoff = (size_t)((step+1) & 1) * HBUF_HALF + hload_base;
            const short* hcl = hloc + hoff;
            const short* hcr = hrem + hoff;
#pragma unroll
            for (int c = 0; c < 8; c++)
                asm volatile("global_load_dwordx4 %0, %1, off sc0"
                             : "=v"(hl[c]) : "v"(hcl + c*128) : "memory");
            // gi loads (normal cached; overlap with h flight)
#pragma unroll
            for (int j = 0; j < 4; j++) {
                ob[j] = (unsigned)(((g*16 + lr*4 + j) * T_ + tt) * H_ + col);
                gi[j] = out[ob[j]];
            }
            const unsigned pat = (unsigned)((epv & 1) | (((epv >> 1) & 1) << 16));
            unsigned pend = 0;
            asm volatile("s_waitcnt vmcnt(4)" ::: "memory");   // h done, gi flying
            __builtin_amdgcn_sched_barrier(0);
#pragma unroll
            for (int c = 0; c < 8; c++) {
                u32x4 d = __builtin_bit_cast(u32x4, hl[c]);
                unsigned m = ((d[0] & 0x00010001u) ^ pat) | ((d[1] & 0x00010001u) ^ pat)
                           | ((d[2] & 0x00010001u) ^ pat) | ((d[3] & 0x00010001u) ^ pat);
                if (!__all(m == 0)) pend |= 1u << c;
            }
            int rounds = 0;
            while (pend) {   // retry stale slots until producer stores land
                if (rounds < LOCAL_ROUNDS) {
                    // L2-scope poll of local buffer (hits producer's store if
                    // same XCD; retries are cheap L2 hits)
#pragma unroll
                    for (int c = 0; c < 8; c++)
                        if (pend & (1u << c))
                            asm volatile("global_load_dwordx4 %0, %1, off sc0"
                                         : "=v"(hl[c]) : "v"(hcl + c*128) : "memory");
                } else {
                    // escalation: device-scope poll of fallback buffer —
                    // guaranteed to observe the producer's sc0 sc1 store
#pragma unroll
                    for (int c = 0; c < 8; c++)
                        if (pend & (1u << c))
                            asm volatile("global_load_dwordx4 %0, %1, off sc0 sc1"
                                         : "=v"(hl[c]) : "v"(hcr + c*128) : "memory");
                }
                asm volatile("s_waitcnt vmcnt(0)" ::: "memory");
                __builtin_amdgcn_sched_barrier(0);
#pragma unroll
                for (int c = 0; c < 8; c++) {
                    if (pend & (1u << c)) {
                        u32x4 d = __builtin_bit_cast(u32x4, hl[c]);
                        unsigned m = ((d[0] & 0x00010001u) ^ pat) | ((d[1] & 0x00010001u) ^ pat)
                                   | ((d[2] & 0x00010001u) ^ pat) | ((d[3] & 0x00010001u) ^ pat);
                        if (__all(m == 0)) pend &= ~(1u << c);
                    }
                }
                rounds++;
            }
            // stage to LDS, swizzled: granule g8 -> g8 ^ (row & 15)
#pragma unroll
            for (int c = 0; c < 8; c++) {
                bf16x4 lo = { hl[c][0], hl[c][1], hl[c][2], hl[c][3] };
                bf16x4 hi = { hl[c][4], hl[c][5], hl[c][6], hl[c][7] };
                const int g8 = (sg + c*16) * 2;
                *reinterpret_cast<bf16x4*>(&hB[sb*1024 + (((g8    ) ^ sb) << 2)]) = lo;
                *reinterpret_cast<bf16x4*>(&hB[sb*1024 + (((g8 + 1) ^ sb) << 2)]) = hi;
            }
            __syncthreads();
            // fragment reads + MFMA (4 independent chains)
            f32x4 a0 = (f32x4){0,0,0,0}, a1 = (f32x4){0,0,0,0};
            f32x4 a2 = (f32x4){0,0,0,0}, a3 = (f32x4){0,0,0,0};
#pragma unroll
            for (int kc = 0; kc < 32; kc += 4) {
#pragma unroll
                for (int q = 0; q < 4; q++) {
                    const int k8 = (kc + q) * 8 + lr * 2;
                    bf16x4 lo = *reinterpret_cast<const bf16x4*>(&hB[lc*1024 + (((k8    ) ^ lc) << 2)]);
                    bf16x4 hi = *reinterpret_cast<const bf16x4*>(&hB[lc*1024 + (((k8 + 1) ^ lc) << 2)]);
                    bf16x8 hf = { lo[0], lo[1], lo[2], lo[3], hi[0], hi[1], hi[2], hi[3] };
                    f32x4& aq = (q == 0) ? a0 : (q == 1) ? a1 : (q == 2) ? a2 : a3;
                    aq = __builtin_amdgcn_mfma_f32_16x16x32_f16(
                        __builtin_bit_cast(f16x8, hf),
                        __builtin_bit_cast(f16x8, breg[kc + q]), aq, 0, 0, 0);
                }
            }
            acc = (a0 + a1) + (a2 + a3);
        } else {
#pragma unroll
            for (int j = 0; j < 4; j++) {
                ob[j] = (unsigned)(((g*16 + lr*4 + j) * T_ + tt) * H_ + col);
                gi[j] = out[ob[j]];
            }
        }

        // h = tanh(acc + gi); fp16 + epoch LSB; transpose via LDS
        const unsigned short ebit = (unsigned short)((lc & 1) ? ((epw >> 1) & 1) : (epw & 1));
        float hv[4];
#pragma unroll
        for (int j = 0; j < 4; j++) {
            hv[j] = tanh_fast(acc[j] + gi[j]);
            unsigned short u = __builtin_bit_cast(unsigned short, (_Float16)hv[j]);
            u = (unsigned short)((u & 0xFFFEu) | ebit);
            htr[(lr*4 + j)*68 + w*16 + lc] = (short)u;
        }
        __syncthreads();   // htr ready AND all waves done with hB reads

        if (step < HALF_ - 1) {   // producer dual-store: local (L2) + fallback (device)
            bf16x4 v = *reinterpret_cast<bf16x4*>(&htr[sb*68 + sg*4]);
            const size_t off = (size_t)(step & 1) * HBUF_HALF + hstore_off;
            short* hnl = hloc + off;
            short* hnr = hrem + off;
            asm volatile("global_store_dwordx2 %0, %1, off sc0"
                         :: "v"(hnl), "v"(v) : "memory");
            asm volatile("global_store_dwordx2 %0, %1, off sc0 sc1"
                         :: "v"(hnr), "v"(v) : "memory");
        }

        // off-critical-path state stores
#pragma unroll
        for (int j = 0; j < 4; j++) {
            out[ob[j]] = hv[j];
            if (p == 0 && step == HALF_ - 1)
                out[(unsigned)(B_*T_*H_) + (unsigned)((g*16 + lr*4 + j) * H_ + col)] = hv[j];
        }
    }
}

extern "C" void kernel_launch(void* const* d_in, const int* in_sizes, int n_in,
                              void* d_out, int out_size, void* d_ws, size_t ws_size,
                              hipStream_t stream) {
    const float* X   = (const float*)d_in[0];
    const float* Wih = (const float*)d_in[1];
    const float* Whh = (const float*)d_in[2];
    const float* bih = (const float*)d_in[3];
    const float* bhh = (const float*)d_in[4];
    float* out = (float*)d_out;

    short* hloc = (short*)d_ws;                 // L2-scope exchange buffer, 512 KB
    short* hrem = hloc + 2 * HBUF_HALF;         // device-scope fallback,    512 KB

    // Epoch 0 is invalid: zeroing both buffers rejects cross-graph-replay
    // leftovers (1 MB total).
    hipMemsetAsync(d_ws, 0, (size_t)2 * HBUF_HALF * 2 * 2, stream);
    gi_gemm<<<dim3(4096), dim3(256), 0, stream>>>(X, Wih, bih, bhh, out);
    rnn_scan<<<dim3(NWG_SCAN), dim3(256), 0, stream>>>(Whh, out, hloc, hrem);
}

// Round 2
// 3477.118 us; speedup vs baseline: 1.2518x; 1.2518x over previous
//
#include <hip/hip_runtime.h>

#define B_    64
#define T_    1024
#define H_    1024
#define HALF_ 512
#define NWG_SCAN 64
#define HBUF_HALF 131072   // shorts per double-buffer half: 2*64*1024

typedef short bf16x8 __attribute__((ext_vector_type(8)));
typedef short bf16x4 __attribute__((ext_vector_type(4)));
typedef _Float16 f16x8 __attribute__((ext_vector_type(8)));
typedef float f32x4  __attribute__((ext_vector_type(4)));
typedef unsigned int u32x4 __attribute__((ext_vector_type(4)));

__device__ __forceinline__ short f2bf(float f) {
    unsigned u = __builtin_bit_cast(unsigned, f);
    u += 0x7fffu + ((u >> 16) & 1u);
    return (short)(u >> 16);
}

__device__ __forceinline__ short f2h(float f) {
    return (short)__builtin_bit_cast(unsigned short, (_Float16)f);
}

__device__ __forceinline__ float tanh_fast(float x) {
    return 1.0f - 2.0f / (__expf(2.0f * x) + 1.0f);
}

// ---------------- Phase 1: gi = bf16(x) @ bf16(W_ih)^T + (b_ih + b_hh) --------
__global__ __launch_bounds__(256) void gi_gemm(
        const float* __restrict__ X, const float* __restrict__ Wih,
        const float* __restrict__ bih, const float* __restrict__ bhh,
        float* __restrict__ out) {
    __shared__ short As[128][40];
    __shared__ short Bs[128][40];
    const int bid = blockIdx.x;
    const int tn = bid & 7;
    const int tm = bid >> 3;
    const int tid = threadIdx.x;
    const int l  = tid & 63;
    const int w  = tid >> 6;
    const int wr = w >> 1, wc = w & 1;
    const int lc = l & 15,  lr = l >> 4;

    const float* Ab = X   + (size_t)tm * 128 * 1024;
    const float* Bb = Wih + (size_t)tn * 128 * 1024;
    const int srow = tid >> 3;
    const int sc4  = (tid & 7) * 4;

    f32x4 acc[4][4];
#pragma unroll
    for (int m = 0; m < 4; m++)
#pragma unroll
        for (int n = 0; n < 4; n++) acc[m][n] = (f32x4){0.f, 0.f, 0.f, 0.f};

    f32x4 ra[4], rb[4];
#pragma unroll
    for (int c = 0; c < 4; c++) {
        ra[c] = *reinterpret_cast<const f32x4*>(Ab + (size_t)(srow + 32*c) * 1024 + sc4);
        rb[c] = *reinterpret_cast<const f32x4*>(Bb + (size_t)(srow + 32*c) * 1024 + sc4);
    }

    for (int k0 = 0; k0 < 1024; k0 += 32) {
        __syncthreads();
#pragma unroll
        for (int c = 0; c < 4; c++) {
            bf16x4 va = { f2bf(ra[c].x), f2bf(ra[c].y), f2bf(ra[c].z), f2bf(ra[c].w) };
            bf16x4 vb = { f2bf(rb[c].x), f2bf(rb[c].y), f2bf(rb[c].z), f2bf(rb[c].w) };
            *reinterpret_cast<bf16x4*>(&As[srow + 32*c][sc4]) = va;
            *reinterpret_cast<bf16x4*>(&Bs[srow + 32*c][sc4]) = vb;
        }
        __syncthreads();
        if (k0 + 32 < 1024) {
            const float* Ak = Ab + k0 + 32;
            const float* Bk = Bb + k0 + 32;
#pragma unroll
            for (int c = 0; c < 4; c++) {
                ra[c] = *reinterpret_cast<const f32x4*>(Ak + (size_t)(srow + 32*c) * 1024 + sc4);
                rb[c] = *reinterpret_cast<const f32x4*>(Bk + (size_t)(srow + 32*c) * 1024 + sc4);
            }
        }
        bf16x8 af[4], bfr[4];
#pragma unroll
        for (int m = 0; m < 4; m++)
            af[m] = *reinterpret_cast<bf16x8*>(&As[wr*64 + m*16 + lc][lr*8]);
#pragma unroll
        for (int n = 0; n < 4; n++)
            bfr[n] = *reinterpret_cast<bf16x8*>(&Bs[wc*64 + n*16 + lc][lr*8]);
#pragma unroll
        for (int m = 0; m < 4; m++)
#pragma unroll
            for (int n = 0; n < 4; n++)
                acc[m][n] = __builtin_amdgcn_mfma_f32_16x16x32_bf16(af[m], bfr[n], acc[m][n], 0, 0, 0);
    }

#pragma unroll
    for (int n = 0; n < 4; n++) {
        const int col = tn*128 + wc*64 + n*16 + lc;
        const float bs = bih[col] + bhh[col];
#pragma unroll
        for (int m = 0; m < 4; m++) {
            const int row0 = tm*128 + wr*64 + m*16 + lr*4;
#pragma unroll
            for (int j = 0; j < 4; j++)
                out[(size_t)(row0 + j) * 1024 + col] = acc[m][n][j] + bs;
        }
    }
}

// ---------------- Phase 2: batch-partitioned barrier-free scan ---------------
// Dual-chain latency hiding: each WG runs BOTH parity chains (p=0,1), which
// are independent recurrences sharing the same register-resident W_hh column
// slice. Chain A's device-scope store -> Infinity-Cache visibility window is
// covered by executing chain B's entire phase (poll+MFMA+tanh), and vice
// versa: steady-state per-step cost drops from V+C to max(C,(V+C)/2). All
// exchange is device-scope (sc0 sc1) -> zero placement assumptions. Epoch-LSB
// protocol unchanged (epoch = step%3+1, 0 invalid; hbuf zeroed per launch).
// W tile register-resident per wave. LDS h tile XOR-swizzled (g8 ^= row).
__global__ __launch_bounds__(256, 1) void rnn_scan(
        const float* __restrict__ Whh, float* __restrict__ out,
        short* __restrict__ hbuf) {
    __shared__ short hB[16 * 1024];   // h stage [16 batch][1024 k], swizzled
    __shared__ short htr[16 * 68];    // output transpose [batch][col+pad]
    const int wg = blockIdx.x;
    const int g  = (wg >> 4) & 3;     // batch group (16 batches)
    const int s  = wg & 15;           // col slice (64 cols)
    const int tid = threadIdx.x;
    const int l  = tid & 63;
    const int w  = tid >> 6;
    const int lc = l & 15, lr = l >> 4;
    const int sb = tid >> 4;          // staging batch row 0..15
    const int sg = tid & 15;          // staging granule index

    // W_hh rows [s*64 + w*16 + lc], fp32 -> fp16, direct to 128 VGPRs
    bf16x8 breg[32];
    {
        const float* wrow = Whh + (size_t)(s*64 + w*16 + lc) * 1024;
#pragma unroll
        for (int kc = 0; kc < 32; kc++) {
            f32x4 v0 = *reinterpret_cast<const f32x4*>(wrow + kc*32 + lr*8);
            f32x4 v1 = *reinterpret_cast<const f32x4*>(wrow + kc*32 + lr*8 + 4);
            bf16x8 q = { f2h(v0.x), f2h(v0.y), f2h(v0.z), f2h(v0.w),
                         f2h(v1.x), f2h(v1.y), f2h(v1.z), f2h(v1.w) };
            breg[kc] = q;
        }
    }

    const int col = s*64 + w*16 + lc;

    for (int step = 0; step < HALF_; step++) {
        const int epw = step % 3 + 1;
        const int epv = (step + 2) % 3 + 1;   // prev step's epw
#pragma unroll
        for (int p = 0; p < 2; p++) {         // two independent parity chains
            const int tt = (p == 0) ? (2*step) : (step == 0 ? T_-1 : 2*step - 1);
            const unsigned hload_base = (unsigned)((p*64 + g*16 + sb) * 1024 + sg*8);
            const unsigned hstore_off = (unsigned)((p*64 + g*16 + sb) * 1024 + s*64 + sg*4);
            f32x4 acc = (f32x4){0.f, 0.f, 0.f, 0.f};
            float gi[4]; unsigned ob[4];

            if (step) {
                // 8 x 16B loads of this group's h (contiguous 32 KB per WG)
                bf16x8 hl[8];
                const short* hc = hbuf + (size_t)((step+1) & 1) * HBUF_HALF + hload_base;
#pragma unroll
                for (int c = 0; c < 8; c++)
                    asm volatile("global_load_dwordx4 %0, %1, off sc0 sc1"
                                 : "=v"(hl[c]) : "v"(hc + c*128) : "memory");
                // gi loads (normal cached; overlap with h flight)
#pragma unroll
                for (int j = 0; j < 4; j++) {
                    ob[j] = (unsigned)(((g*16 + lr*4 + j) * T_ + tt) * H_ + col);
                    gi[j] = out[ob[j]];
                }
                const unsigned pat = (unsigned)((epv & 1) | (((epv >> 1) & 1) << 16));
                unsigned pend = 0;
                asm volatile("s_waitcnt vmcnt(4)" ::: "memory");   // h done, gi flying
                __builtin_amdgcn_sched_barrier(0);
#pragma unroll
                for (int c = 0; c < 8; c++) {
                    u32x4 d = __builtin_bit_cast(u32x4, hl[c]);
                    unsigned m = ((d[0] & 0x00010001u) ^ pat) | ((d[1] & 0x00010001u) ^ pat)
                               | ((d[2] & 0x00010001u) ^ pat) | ((d[3] & 0x00010001u) ^ pat);
                    if (!__all(m == 0)) pend |= 1u << c;
                }
                while (pend) {   // retry stale slots until producer stores land
#pragma unroll
                    for (int c = 0; c < 8; c++)
                        if (pend & (1u << c))
                            asm volatile("global_load_dwordx4 %0, %1, off sc0 sc1"
                                         : "=v"(hl[c]) : "v"(hc + c*128) : "memory");
                    asm volatile("s_waitcnt vmcnt(0)" ::: "memory");
                    __builtin_amdgcn_sched_barrier(0);
#pragma unroll
                    for (int c = 0; c < 8; c++) {
                        if (pend & (1u << c)) {
                            u32x4 d = __builtin_bit_cast(u32x4, hl[c]);
                            unsigned m = ((d[0] & 0x00010001u) ^ pat) | ((d[1] & 0x00010001u) ^ pat)
                                       | ((d[2] & 0x00010001u) ^ pat) | ((d[3] & 0x00010001u) ^ pat);
                            if (__all(m == 0)) pend &= ~(1u << c);
                        }
                    }
                }
                // stage to LDS, swizzled: granule g8 -> g8 ^ (row & 15)
#pragma unroll
                for (int c = 0; c < 8; c++) {
                    bf16x4 lo = { hl[c][0], hl[c][1], hl[c][2], hl[c][3] };
                    bf16x4 hi = { hl[c][4], hl[c][5], hl[c][6], hl[c][7] };
                    const int g8 = (sg + c*16) * 2;
                    *reinterpret_cast<bf16x4*>(&hB[sb*1024 + (((g8    ) ^ sb) << 2)]) = lo;
                    *reinterpret_cast<bf16x4*>(&hB[sb*1024 + (((g8 + 1) ^ sb) << 2)]) = hi;
                }
                __syncthreads();
                // fragment reads + MFMA (4 independent chains)
                f32x4 a0 = (f32x4){0,0,0,0}, a1 = (f32x4){0,0,0,0};
                f32x4 a2 = (f32x4){0,0,0,0}, a3 = (f32x4){0,0,0,0};
#pragma unroll
                for (int kc = 0; kc < 32; kc += 4) {
#pragma unroll
                    for (int q = 0; q < 4; q++) {
                        const int k8 = (kc + q) * 8 + lr * 2;
                        bf16x4 lo = *reinterpret_cast<const bf16x4*>(&hB[lc*1024 + (((k8    ) ^ lc) << 2)]);
                        bf16x4 hi = *reinterpret_cast<const bf16x4*>(&hB[lc*1024 + (((k8 + 1) ^ lc) << 2)]);
                        bf16x8 hf = { lo[0], lo[1], lo[2], lo[3], hi[0], hi[1], hi[2], hi[3] };
                        f32x4& aq = (q == 0) ? a0 : (q == 1) ? a1 : (q == 2) ? a2 : a3;
                        aq = __builtin_amdgcn_mfma_f32_16x16x32_f16(
                            __builtin_bit_cast(f16x8, hf),
                            __builtin_bit_cast(f16x8, breg[kc + q]), aq, 0, 0, 0);
                    }
                }
                acc = (a0 + a1) + (a2 + a3);
            } else {
#pragma unroll
                for (int j = 0; j < 4; j++) {
                    ob[j] = (unsigned)(((g*16 + lr*4 + j) * T_ + tt) * H_ + col);
                    gi[j] = out[ob[j]];
                }
            }

            // h = tanh(acc + gi); fp16 + epoch LSB; transpose via LDS
            const unsigned short ebit = (unsigned short)((lc & 1) ? ((epw >> 1) & 1) : (epw & 1));
            float hv[4];
#pragma unroll
            for (int j = 0; j < 4; j++) {
                hv[j] = tanh_fast(acc[j] + gi[j]);
                unsigned short u = __builtin_bit_cast(unsigned short, (_Float16)hv[j]);
                u = (unsigned short)((u & 0xFFFEu) | ebit);
                htr[(lr*4 + j)*68 + w*16 + lc] = (short)u;
            }
            __syncthreads();   // htr ready AND all waves done with hB reads

            if (step < HALF_ - 1) {   // producer store: one 8B dword-pair per thread
                bf16x4 v = *reinterpret_cast<bf16x4*>(&htr[sb*68 + sg*4]);
                short* hn = hbuf + (size_t)(step & 1) * HBUF_HALF + hstore_off;
                asm volatile("global_store_dwordx2 %0, %1, off sc0 sc1"
                             :: "v"(hn), "v"(v) : "memory");
            }

            // off-critical-path state stores
#pragma unroll
            for (int j = 0; j < 4; j++) {
                out[ob[j]] = hv[j];
                if (p == 0 && step == HALF_ - 1)
                    out[(unsigned)(B_*T_*H_) + (unsigned)((g*16 + lr*4 + j) * H_ + col)] = hv[j];
            }
        }
    }
}

extern "C" void kernel_launch(void* const* d_in, const int* in_sizes, int n_in,
                              void* d_out, int out_size, void* d_ws, size_t ws_size,
                              hipStream_t stream) {
    const float* X   = (const float*)d_in[0];
    const float* Wih = (const float*)d_in[1];
    const float* Whh = (const float*)d_in[2];
    const float* bih = (const float*)d_in[3];
    const float* bhh = (const float*)d_in[4];
    float* out = (float*)d_out;

    short* hbuf = (short*)d_ws;   // [2 dbuf][2 p][64 b][1024] fp16 = 512 KB

    // Epoch 0 is invalid: zeroing hbuf rejects cross-graph-replay leftovers.
    hipMemsetAsync(hbuf, 0, (size_t)2 * HBUF_HALF * 2, stream);
    gi_gemm<<<dim3(4096), dim3(256), 0, stream>>>(X, Wih, bih, bhh, out);
    rnn_scan<<<dim3(NWG_SCAN), dim3(256), 0, stream>>>(Whh, out, hbuf);
}

// Round 3
// 2287.063 us; speedup vs baseline: 1.9031x; 1.5203x over previous
//
#include <hip/hip_runtime.h>

#define B_    64
#define T_    1024
#define H_    1024
#define HALF_ 512
#define NWG_SCAN 128
#define HBUF_HALF 131072   // shorts per double-buffer half: 2*64*1024

typedef short bf16x8 __attribute__((ext_vector_type(8)));
typedef short bf16x4 __attribute__((ext_vector_type(4)));
typedef _Float16 f16x8 __attribute__((ext_vector_type(8)));
typedef float f32x4  __attribute__((ext_vector_type(4)));
typedef unsigned int u32x4 __attribute__((ext_vector_type(4)));

__device__ __forceinline__ short f2bf(float f) {
    unsigned u = __builtin_bit_cast(unsigned, f);
    u += 0x7fffu + ((u >> 16) & 1u);
    return (short)(u >> 16);
}

__device__ __forceinline__ short f2h(float f) {
    return (short)__builtin_bit_cast(unsigned short, (_Float16)f);
}

__device__ __forceinline__ float tanh_fast(float x) {
    return 1.0f - 2.0f / (__expf(2.0f * x) + 1.0f);
}

// LDS-only barrier: no vmcnt drain (hipcc's __syncthreads emits
// s_waitcnt vmcnt(0) before s_barrier, serializing every step on the
// previous step's store retirement — the hidden ~1us/step cost).
#define BAR() do { \
    __builtin_amdgcn_sched_barrier(0); \
    asm volatile("s_waitcnt lgkmcnt(0)" ::: "memory"); \
    __builtin_amdgcn_sched_barrier(0); \
    __builtin_amdgcn_s_barrier(); \
    __builtin_amdgcn_sched_barrier(0); \
} while (0)

// ---------------- Phase 1: gi = bf16(x) @ bf16(W_ih)^T + (b_ih + b_hh) --------
__global__ __launch_bounds__(256) void gi_gemm(
        const float* __restrict__ X, const float* __restrict__ Wih,
        const float* __restrict__ bih, const float* __restrict__ bhh,
        float* __restrict__ out) {
    __shared__ short As[128][40];
    __shared__ short Bs[128][40];
    const int bid = blockIdx.x;
    const int tn = bid & 7;
    const int tm = bid >> 3;
    const int tid = threadIdx.x;
    const int l  = tid & 63;
    const int w  = tid >> 6;
    const int wr = w >> 1, wc = w & 1;
    const int lc = l & 15,  lr = l >> 4;

    const float* Ab = X   + (size_t)tm * 128 * 1024;
    const float* Bb = Wih + (size_t)tn * 128 * 1024;
    const int srow = tid >> 3;
    const int sc4  = (tid & 7) * 4;

    f32x4 acc[4][4];
#pragma unroll
    for (int m = 0; m < 4; m++)
#pragma unroll
        for (int n = 0; n < 4; n++) acc[m][n] = (f32x4){0.f, 0.f, 0.f, 0.f};

    f32x4 ra[4], rb[4];
#pragma unroll
    for (int c = 0; c < 4; c++) {
        ra[c] = *reinterpret_cast<const f32x4*>(Ab + (size_t)(srow + 32*c) * 1024 + sc4);
        rb[c] = *reinterpret_cast<const f32x4*>(Bb + (size_t)(srow + 32*c) * 1024 + sc4);
    }

    for (int k0 = 0; k0 < 1024; k0 += 32) {
        __syncthreads();
#pragma unroll
        for (int c = 0; c < 4; c++) {
            bf16x4 va = { f2bf(ra[c].x), f2bf(ra[c].y), f2bf(ra[c].z), f2bf(ra[c].w) };
            bf16x4 vb = { f2bf(rb[c].x), f2bf(rb[c].y), f2bf(rb[c].z), f2bf(rb[c].w) };
            *reinterpret_cast<bf16x4*>(&As[srow + 32*c][sc4]) = va;
            *reinterpret_cast<bf16x4*>(&Bs[srow + 32*c][sc4]) = vb;
        }
        __syncthreads();
        if (k0 + 32 < 1024) {
            const float* Ak = Ab + k0 + 32;
            const float* Bk = Bb + k0 + 32;
#pragma unroll
            for (int c = 0; c < 4; c++) {
                ra[c] = *reinterpret_cast<const f32x4*>(Ak + (size_t)(srow + 32*c) * 1024 + sc4);
                rb[c] = *reinterpret_cast<const f32x4*>(Bk + (size_t)(srow + 32*c) * 1024 + sc4);
            }
        }
        bf16x8 af[4], bfr[4];
#pragma unroll
        for (int m = 0; m < 4; m++)
            af[m] = *reinterpret_cast<bf16x8*>(&As[wr*64 + m*16 + lc][lr*8]);
#pragma unroll
        for (int n = 0; n < 4; n++)
            bfr[n] = *reinterpret_cast<bf16x8*>(&Bs[wc*64 + n*16 + lc][lr*8]);
#pragma unroll
        for (int m = 0; m < 4; m++)
#pragma unroll
            for (int n = 0; n < 4; n++)
                acc[m][n] = __builtin_amdgcn_mfma_f32_16x16x32_bf16(af[m], bfr[n], acc[m][n], 0, 0, 0);
    }

#pragma unroll
    for (int n = 0; n < 4; n++) {
        const int col = tn*128 + wc*64 + n*16 + lc;
        const float bs = bih[col] + bhh[col];
#pragma unroll
        for (int m = 0; m < 4; m++) {
            const int row0 = tm*128 + wr*64 + m*16 + lr*4;
#pragma unroll
            for (int j = 0; j < 4; j++)
                out[(size_t)(row0 + j) * 1024 + col] = acc[m][n][j] + bs;
        }
    }
}

// ---------------- Phase 2: batch-partitioned barrier-free scan ---------------
// Proven 128-WG topology with the per-step serializers removed:
//  (1) raw LDS-only barriers (no vmcnt(0) drain per step),
//  (2) gi+h loads for step n+1 issued BEFORE step n's stores; at step n+1's
//      top s_waitcnt vmcnt(2) waits for exactly the 12 loads (the 2 stores
//      are newest in the FIFO and excluded),
//  (3) out[] stores coalesced to one dwordx4/thread via f32 LDS transpose.
// Epoch-LSB protocol unchanged (epoch = step%3+1, 0 invalid; hbuf zeroed per
// launch; stale/unarrived registers fail the epoch check and are retried).
#define STEP_BODY(STEP_, GIC_, GIN_)                                           \
{                                                                              \
    const int step = (STEP_);                                                  \
    const int epw = step % 3 + 1;                                              \
    const int epv = (step + 2) % 3 + 1;                                        \
    f32x4 acc;                                                                 \
    if (step) {                                                                \
        asm volatile("s_waitcnt vmcnt(2)" ::: "memory");                       \
        __builtin_amdgcn_sched_barrier(0);                                     \
        const unsigned pat = (unsigned)((epv & 1) | (((epv >> 1) & 1) << 16)); \
        unsigned pend = 0;                                                     \
        _Pragma("unroll")                                                      \
        for (int c = 0; c < 8; c++) {                                          \
            u32x4 d = __builtin_bit_cast(u32x4, hl[c]);                        \
            unsigned m = ((d[0] & 0x00010001u) ^ pat) | ((d[1] & 0x00010001u) ^ pat)  \
                       | ((d[2] & 0x00010001u) ^ pat) | ((d[3] & 0x00010001u) ^ pat); \
            if (!__all(m == 0)) pend |= 1u << c;                               \
        }                                                                      \
        const short* hc = hbuf + (size_t)((step+1) & 1) * HBUF_HALF + hload_base; \
        while (pend) {                                                         \
            _Pragma("unroll")                                                  \
            for (int c = 0; c < 8; c++)                                        \
                if (pend & (1u << c))                                          \
                    asm volatile("global_load_dwordx4 %0, %1, off sc0 sc1"     \
                                 : "=v"(hl[c]) : "v"(hc + c*128) : "memory");  \
            asm volatile("s_waitcnt vmcnt(0)" ::: "memory");                   \
            __builtin_amdgcn_sched_barrier(0);                                 \
            _Pragma("unroll")                                                  \
            for (int c = 0; c < 8; c++) {                                      \
                if (pend & (1u << c)) {                                        \
                    u32x4 d = __builtin_bit_cast(u32x4, hl[c]);                \
                    unsigned m = ((d[0] & 0x00010001u) ^ pat) | ((d[1] & 0x00010001u) ^ pat)  \
                               | ((d[2] & 0x00010001u) ^ pat) | ((d[3] & 0x00010001u) ^ pat); \
                    if (__all(m == 0)) pend &= ~(1u << c);                     \
                }                                                              \
            }                                                                  \
        }                                                                      \
        _Pragma("unroll")                                                      \
        for (int c = 0; c < 8; c++) {                                          \
            bf16x4 lo = { hl[c][0], hl[c][1], hl[c][2], hl[c][3] };            \
            bf16x4 hi = { hl[c][4], hl[c][5], hl[c][6], hl[c][7] };            \
            const int g8 = (sg + c*16) * 2;                                    \
            *reinterpret_cast<bf16x4*>(&hB[sb*1024 + (((g8    ) ^ sb) << 2)]) = lo; \
            *reinterpret_cast<bf16x4*>(&hB[sb*1024 + (((g8 + 1) ^ sb) << 2)]) = hi; \
        }                                                                      \
        BAR();                                                                 \
        f32x4 a0 = (f32x4){0,0,0,0}, a1 = (f32x4){0,0,0,0};                    \
        f32x4 a2 = (f32x4){0,0,0,0}, a3 = (f32x4){0,0,0,0};                    \
        _Pragma("unroll")                                                      \
        for (int kc = 0; kc < 32; kc += 4) {                                   \
            _Pragma("unroll")                                                  \
            for (int q = 0; q < 4; q++) {                                      \
                const int k8 = (kc + q) * 8 + lr * 2;                          \
                bf16x4 lo = *reinterpret_cast<const bf16x4*>(&hB[lc*1024 + (((k8    ) ^ lc) << 2)]); \
                bf16x4 hi = *reinterpret_cast<const bf16x4*>(&hB[lc*1024 + (((k8 + 1) ^ lc) << 2)]); \
                bf16x8 hf = { lo[0], lo[1], lo[2], lo[3], hi[0], hi[1], hi[2], hi[3] }; \
                f32x4& aq = (q == 0) ? a0 : (q == 1) ? a1 : (q == 2) ? a2 : a3; \
                aq = __builtin_amdgcn_mfma_f32_16x16x32_f16(                   \
                    __builtin_bit_cast(f16x8, hf),                             \
                    __builtin_bit_cast(f16x8, breg[kc + q]), aq, 0, 0, 0);     \
            }                                                                  \
        }                                                                      \
        acc = (a0 + a1) + (a2 + a3);                                           \
    } else {                                                                   \
        asm volatile("s_waitcnt vmcnt(0)" ::: "memory");                       \
        __builtin_amdgcn_sched_barrier(0);                                     \
        acc = (f32x4){0.f, 0.f, 0.f, 0.f};                                     \
    }                                                                          \
    /* prefetch gi+h for step+1 BEFORE this step's stores */                   \
    if (step + 1 < HALF_) {                                                    \
        const int t2 = (p == 0) ? (2*(step+1)) : (2*(step+1) - 1);             \
        _Pragma("unroll")                                                      \
        for (int j = 0; j < 4; j++) {                                          \
            const float* ga = out + (size_t)(((g*16 + lr*4 + j) * T_ + t2) * H_ + col); \
            asm volatile("global_load_dword %0, %1, off"                       \
                         : "=v"(GIN_[j]) : "v"(ga) : "memory");                \
        }                                                                      \
        const short* hc2 = hbuf + (size_t)(step & 1) * HBUF_HALF + hload_base; \
        _Pragma("unroll")                                                      \
        for (int c = 0; c < 8; c++)                                            \
            asm volatile("global_load_dwordx4 %0, %1, off sc0 sc1"             \
                         : "=v"(hl[c]) : "v"(hc2 + c*128) : "memory");         \
    }                                                                          \
    /* h = tanh(acc + gi); fp16 + epoch LSB; transposes via LDS */             \
    const int tt = (p == 0) ? (2*step) : (step == 0 ? T_-1 : 2*step - 1);      \
    const unsigned short ebit = (unsigned short)((lc & 1) ? ((epw >> 1) & 1) : (epw & 1)); \
    _Pragma("unroll")                                                          \
    for (int j = 0; j < 4; j++) {                                              \
        float hv = tanh_fast(acc[j] + GIC_[j]);                                \
        unsigned short u = __builtin_bit_cast(unsigned short, (_Float16)hv);   \
        u = (unsigned short)((u & 0xFFFEu) | ebit);                            \
        htr [(lr*4 + j)*68 + w*16 + lc] = (short)u;                            \
        htrF[(lr*4 + j)*68 + w*16 + lc] = hv;                                  \
    }                                                                          \
    BAR();                                                                     \
    if (step < HALF_ - 1) {                                                    \
        bf16x4 v = *reinterpret_cast<bf16x4*>(&htr[sb*68 + sg*4]);             \
        short* hn = hbuf + (size_t)(step & 1) * HBUF_HALF + hstore_off;        \
        asm volatile("global_store_dwordx2 %0, %1, off sc0 sc1"                \
                     :: "v"(hn), "v"(v) : "memory");                           \
    }                                                                          \
    {                                                                          \
        f32x4 ov = *reinterpret_cast<f32x4*>(&htrF[sb*68 + sg*4]);             \
        float* op_ = out + (size_t)(((g*16 + sb) * T_ + tt) * H_ + s*64 + sg*4); \
        asm volatile("global_store_dwordx4 %0, %1, off"                        \
                     :: "v"(op_), "v"(ov) : "memory");                         \
        if (p == 0 && step == HALF_ - 1) {                                     \
            float* fp_ = out + (size_t)B_*T_*H_ + (size_t)((g*16 + sb) * H_ + s*64 + sg*4); \
            asm volatile("global_store_dwordx4 %0, %1, off"                    \
                         :: "v"(fp_), "v"(ov) : "memory");                     \
        }                                                                      \
    }                                                                          \
}

__global__ __launch_bounds__(256, 1) void rnn_scan(
        const float* __restrict__ Whh, float* __restrict__ out,
        short* __restrict__ hbuf) {
    __shared__ short hB[16 * 1024];   // h stage [16 batch][1024 k], swizzled
    __shared__ short htr[16 * 68];    // fp16+epoch transpose [batch][col+pad]
    __shared__ float htrF[16 * 68];   // f32 transpose for coalesced out stores
    const int wg = blockIdx.x;
    const int p  = wg >> 6;           // parity
    const int g  = (wg >> 4) & 3;     // batch group (16 batches)
    const int s  = wg & 15;           // col slice (64 cols)
    const int tid = threadIdx.x;
    const int l  = tid & 63;
    const int w  = tid >> 6;
    const int lc = l & 15, lr = l >> 4;
    const int sb = tid >> 4;          // staging batch row 0..15
    const int sg = tid & 15;          // staging granule index

    // W_hh rows [s*64 + w*16 + lc], fp32 -> fp16, direct to 128 VGPRs
    bf16x8 breg[32];
    {
        const float* wrow = Whh + (size_t)(s*64 + w*16 + lc) * 1024;
#pragma unroll
        for (int kc = 0; kc < 32; kc++) {
            f32x4 v0 = *reinterpret_cast<const f32x4*>(wrow + kc*32 + lr*8);
            f32x4 v1 = *reinterpret_cast<const f32x4*>(wrow + kc*32 + lr*8 + 4);
            bf16x8 q = { f2h(v0.x), f2h(v0.y), f2h(v0.z), f2h(v0.w),
                         f2h(v1.x), f2h(v1.y), f2h(v1.z), f2h(v1.w) };
            breg[kc] = q;
        }
    }

    const unsigned hload_base = (unsigned)((p*64 + g*16 + sb) * 1024 + sg*8);
    const unsigned hstore_off = (unsigned)((p*64 + g*16 + sb) * 1024 + s*64 + sg*4);
    const int col = s*64 + w*16 + lc;

    bf16x8 hl[8];
    float giA[4], giB[4];

    // prologue: issue gi(0)
    {
        const int t0 = (p == 0) ? 0 : T_ - 1;
#pragma unroll
        for (int j = 0; j < 4; j++) {
            const float* ga = out + (size_t)(((g*16 + lr*4 + j) * T_ + t0) * H_ + col);
            asm volatile("global_load_dword %0, %1, off"
                         : "=v"(giA[j]) : "v"(ga) : "memory");
        }
    }

    for (int sp = 0; sp < HALF_; sp += 2) {
        STEP_BODY(sp,     giA, giB)
        STEP_BODY(sp + 1, giB, giA)
    }
}

extern "C" void kernel_launch(void* const* d_in, const int* in_sizes, int n_in,
                              void* d_out, int out_size, void* d_ws, size_t ws_size,
                              hipStream_t stream) {
    const float* X   = (const float*)d_in[0];
    const float* Wih = (const float*)d_in[1];
    const float* Whh = (const float*)d_in[2];
    const float* bih = (const float*)d_in[3];
    const float* bhh = (const float*)d_in[4];
    float* out = (float*)d_out;

    short* hbuf = (short*)d_ws;   // [2 dbuf][2 p][64 b][1024] fp16 = 512 KB

    // Epoch 0 is invalid: zeroing hbuf rejects cross-graph-replay leftovers.
    hipMemsetAsync(hbuf, 0, (size_t)2 * HBUF_HALF * 2, stream);
    gi_gemm<<<dim3(4096), dim3(256), 0, stream>>>(X, Wih, bih, bhh, out);
    rnn_scan<<<dim3(NWG_SCAN), dim3(256), 0, stream>>>(Whh, out, hbuf);
}

// Round 5
// 2281.471 us; speedup vs baseline: 1.9078x; 1.0025x over previous
//
#include <hip/hip_runtime.h>

#define B_    64
#define T_    1024
#define H_    1024
#define HALF_ 512
#define NWG_SCAN 128
#define HBUF_HALF 131072   // shorts per double-buffer half: 2*64*1024

typedef short bf16x8 __attribute__((ext_vector_type(8)));
typedef short bf16x4 __attribute__((ext_vector_type(4)));
typedef _Float16 f16x8 __attribute__((ext_vector_type(8)));
typedef float f32x4  __attribute__((ext_vector_type(4)));
typedef unsigned int u32x4 __attribute__((ext_vector_type(4)));

__device__ __forceinline__ short f2bf(float f) {
    unsigned u = __builtin_bit_cast(unsigned, f);
    u += 0x7fffu + ((u >> 16) & 1u);
    return (short)(u >> 16);
}

__device__ __forceinline__ short f2h(float f) {
    return (short)__builtin_bit_cast(unsigned short, (_Float16)f);
}

__device__ __forceinline__ float tanh_fast(float x) {
    return 1.0f - 2.0f / (__expf(2.0f * x) + 1.0f);
}

// LDS-only barrier: no vmcnt drain (hipcc's __syncthreads emits
// s_waitcnt vmcnt(0) before s_barrier, serializing every step on the
// previous step's device-scope store retirement).
#define BAR() do { \
    __builtin_amdgcn_sched_barrier(0); \
    asm volatile("s_waitcnt lgkmcnt(0)" ::: "memory"); \
    __builtin_amdgcn_sched_barrier(0); \
    __builtin_amdgcn_s_barrier(); \
    __builtin_amdgcn_sched_barrier(0); \
} while (0)

// ---------------- Phase 1: gi = bf16(x) @ bf16(W_ih)^T + (b_ih + b_hh) --------
__global__ __launch_bounds__(256) void gi_gemm(
        const float* __restrict__ X, const float* __restrict__ Wih,
        const float* __restrict__ bih, const float* __restrict__ bhh,
        float* __restrict__ out) {
    __shared__ short As[128][40];
    __shared__ short Bs[128][40];
    const int bid = blockIdx.x;
    const int tn = bid & 7;
    const int tm = bid >> 3;
    const int tid = threadIdx.x;
    const int l  = tid & 63;
    const int w  = tid >> 6;
    const int wr = w >> 1, wc = w & 1;
    const int lc = l & 15,  lr = l >> 4;

    const float* Ab = X   + (size_t)tm * 128 * 1024;
    const float* Bb = Wih + (size_t)tn * 128 * 1024;
    const int srow = tid >> 3;
    const int sc4  = (tid & 7) * 4;

    f32x4 acc[4][4];
#pragma unroll
    for (int m = 0; m < 4; m++)
#pragma unroll
        for (int n = 0; n < 4; n++) acc[m][n] = (f32x4){0.f, 0.f, 0.f, 0.f};

    f32x4 ra[4], rb[4];
#pragma unroll
    for (int c = 0; c < 4; c++) {
        ra[c] = *reinterpret_cast<const f32x4*>(Ab + (size_t)(srow + 32*c) * 1024 + sc4);
        rb[c] = *reinterpret_cast<const f32x4*>(Bb + (size_t)(srow + 32*c) * 1024 + sc4);
    }

    for (int k0 = 0; k0 < 1024; k0 += 32) {
        __syncthreads();
#pragma unroll
        for (int c = 0; c < 4; c++) {
            bf16x4 va = { f2bf(ra[c].x), f2bf(ra[c].y), f2bf(ra[c].z), f2bf(ra[c].w) };
            bf16x4 vb = { f2bf(rb[c].x), f2bf(rb[c].y), f2bf(rb[c].z), f2bf(rb[c].w) };
            *reinterpret_cast<bf16x4*>(&As[srow + 32*c][sc4]) = va;
            *reinterpret_cast<bf16x4*>(&Bs[srow + 32*c][sc4]) = vb;
        }
        __syncthreads();
        if (k0 + 32 < 1024) {
            const float* Ak = Ab + k0 + 32;
            const float* Bk = Bb + k0 + 32;
#pragma unroll
            for (int c = 0; c < 4; c++) {
                ra[c] = *reinterpret_cast<const f32x4*>(Ak + (size_t)(srow + 32*c) * 1024 + sc4);
                rb[c] = *reinterpret_cast<const f32x4*>(Bk + (size_t)(srow + 32*c) * 1024 + sc4);
            }
        }
        bf16x8 af[4], bfr[4];
#pragma unroll
        for (int m = 0; m < 4; m++)
            af[m] = *reinterpret_cast<bf16x8*>(&As[wr*64 + m*16 + lc][lr*8]);
#pragma unroll
        for (int n = 0; n < 4; n++)
            bfr[n] = *reinterpret_cast<bf16x8*>(&Bs[wc*64 + n*16 + lc][lr*8]);
#pragma unroll
        for (int m = 0; m < 4; m++)
#pragma unroll
            for (int n = 0; n < 4; n++)
                acc[m][n] = __builtin_amdgcn_mfma_f32_16x16x32_bf16(af[m], bfr[n], acc[m][n], 0, 0, 0);
    }

#pragma unroll
    for (int n = 0; n < 4; n++) {
        const int col = tn*128 + wc*64 + n*16 + lc;
        const float bs = bih[col] + bhh[col];
#pragma unroll
        for (int m = 0; m < 4; m++) {
            const int row0 = tm*128 + wr*64 + m*16 + lr*4;
#pragma unroll
            for (int j = 0; j < 4; j++)
                out[(size_t)(row0 + j) * 1024 + col] = acc[m][n][j] + bs;
        }
    }
}

// ---------------- Phase 2: batch-partitioned barrier-free scan ---------------
// Proven 128-WG topology + validated serializer removals, minus the R3
// stale-prefetch mistake:
//  (1) LDS-only barriers: no vmcnt(0) drain per step,
//  (2) h loads issued FRESH at step top (baseline semantics), single
//      vmcnt(0) wait covers loads + folds the previous step's store
//      retirement (unavoidable: vmcnt retires in order),
//  (3) out[] stores coalesced to one dwordx4/thread via f32 LDS transpose,
//  (4) gi for step n+1 register-prefetched after step n's poll (retries
//      never drain it uselessly; it is consumed next step anyway).
// Epoch-LSB protocol unchanged (epoch = step%3+1, 0 invalid; hbuf zeroed per
// launch; stale/unarrived data fails the epoch check and is retried).
#define STEP_BODY(STEP_, GIC_, GIN_)                                           \
{                                                                              \
    const int step = (STEP_);                                                  \
    const int epw = step % 3 + 1;                                              \
    const int epv = (step + 2) % 3 + 1;                                        \
    f32x4 acc;                                                                 \
    if (step) {                                                                \
        const short* hc = hbuf + (size_t)((step+1) & 1) * HBUF_HALF + hload_base; \
        _Pragma("unroll")                                                      \
        for (int c = 0; c < 8; c++)                                            \
            asm volatile("global_load_dwordx4 %0, %1, off sc0 sc1"             \
                         : "=v"(hl[c]) : "v"(hc + c*128) : "memory");          \
        asm volatile("s_waitcnt vmcnt(0)" ::: "memory");                       \
        __builtin_amdgcn_sched_barrier(0);                                     \
        const unsigned pat = (unsigned)((epv & 1) | (((epv >> 1) & 1) << 16)); \
        unsigned pend = 0;                                                     \
        _Pragma("unroll")                                                      \
        for (int c = 0; c < 8; c++) {                                          \
            u32x4 d = __builtin_bit_cast(u32x4, hl[c]);                        \
            unsigned m = ((d[0] & 0x00010001u) ^ pat) | ((d[1] & 0x00010001u) ^ pat)  \
                       | ((d[2] & 0x00010001u) ^ pat) | ((d[3] & 0x00010001u) ^ pat); \
            if (!__all(m == 0)) pend |= 1u << c;                               \
        }                                                                      \
        while (pend) {                                                         \
            _Pragma("unroll")                                                  \
            for (int c = 0; c < 8; c++)                                        \
                if (pend & (1u << c))                                          \
                    asm volatile("global_load_dwordx4 %0, %1, off sc0 sc1"     \
                                 : "=v"(hl[c]) : "v"(hc + c*128) : "memory");  \
            asm volatile("s_waitcnt vmcnt(0)" ::: "memory");                   \
            __builtin_amdgcn_sched_barrier(0);                                 \
            _Pragma("unroll")                                                  \
            for (int c = 0; c < 8; c++) {                                      \
                if (pend & (1u << c)) {                                        \
                    u32x4 d = __builtin_bit_cast(u32x4, hl[c]);                \
                    unsigned m = ((d[0] & 0x00010001u) ^ pat) | ((d[1] & 0x00010001u) ^ pat)  \
                               | ((d[2] & 0x00010001u) ^ pat) | ((d[3] & 0x00010001u) ^ pat); \
                    if (__all(m == 0)) pend &= ~(1u << c);                     \
                }                                                              \
            }                                                                  \
        }                                                                      \
        _Pragma("unroll")                                                      \
        for (int c = 0; c < 8; c++) {                                          \
            bf16x4 lo = { hl[c][0], hl[c][1], hl[c][2], hl[c][3] };            \
            bf16x4 hi = { hl[c][4], hl[c][5], hl[c][6], hl[c][7] };            \
            const int g8 = (sg + c*16) * 2;                                    \
            *reinterpret_cast<bf16x4*>(&hB[sb*1024 + (((g8    ) ^ sb) << 2)]) = lo; \
            *reinterpret_cast<bf16x4*>(&hB[sb*1024 + (((g8 + 1) ^ sb) << 2)]) = hi; \
        }                                                                      \
        BAR();                                                                 \
        f32x4 a0 = (f32x4){0,0,0,0}, a1 = (f32x4){0,0,0,0};                    \
        f32x4 a2 = (f32x4){0,0,0,0}, a3 = (f32x4){0,0,0,0};                    \
        _Pragma("unroll")                                                      \
        for (int kc = 0; kc < 32; kc += 4) {                                   \
            _Pragma("unroll")                                                  \
            for (int q = 0; q < 4; q++) {                                      \
                const int k8 = (kc + q) * 8 + lr * 2;                          \
                bf16x4 lo = *reinterpret_cast<const bf16x4*>(&hB[lc*1024 + (((k8    ) ^ lc) << 2)]); \
                bf16x4 hi = *reinterpret_cast<const bf16x4*>(&hB[lc*1024 + (((k8 + 1) ^ lc) << 2)]); \
                bf16x8 hf = { lo[0], lo[1], lo[2], lo[3], hi[0], hi[1], hi[2], hi[3] }; \
                f32x4& aq = (q == 0) ? a0 : (q == 1) ? a1 : (q == 2) ? a2 : a3; \
                aq = __builtin_amdgcn_mfma_f32_16x16x32_f16(                   \
                    __builtin_bit_cast(f16x8, hf),                             \
                    __builtin_bit_cast(f16x8, breg[kc + q]), aq, 0, 0, 0);     \
            }                                                                  \
        }                                                                      \
        acc = (a0 + a1) + (a2 + a3);                                           \
    } else {                                                                   \
        asm volatile("s_waitcnt vmcnt(0)" ::: "memory");                       \
        __builtin_amdgcn_sched_barrier(0);                                     \
        acc = (f32x4){0.f, 0.f, 0.f, 0.f};                                     \
    }                                                                          \
    /* gi register-prefetch for step+1 (consumed next step; retries done) */   \
    if (step + 1 < HALF_) {                                                    \
        const int t2 = (p == 0) ? (2*(step+1)) : (2*(step+1) - 1);             \
        _Pragma("unroll")                                                      \
        for (int j = 0; j < 4; j++) {                                          \
            const float* ga = out + (size_t)(((g*16 + lr*4 + j) * T_ + t2) * H_ + col); \
            asm volatile("global_load_dword %0, %1, off"                       \
                         : "=v"(GIN_[j]) : "v"(ga) : "memory");                \
        }                                                                      \
    }                                                                          \
    /* h = tanh(acc + gi); fp16 + epoch LSB; transposes via LDS */             \
    const int tt = (p == 0) ? (2*step) : (step == 0 ? T_-1 : 2*step - 1);      \
    const unsigned short ebit = (unsigned short)((lc & 1) ? ((epw >> 1) & 1) : (epw & 1)); \
    _Pragma("unroll")                                                          \
    for (int j = 0; j < 4; j++) {                                              \
        float hv = tanh_fast(acc[j] + GIC_[j]);                                \
        unsigned short u = __builtin_bit_cast(unsigned short, (_Float16)hv);   \
        u = (unsigned short)((u & 0xFFFEu) | ebit);                            \
        htr [(lr*4 + j)*68 + w*16 + lc] = (short)u;                            \
        htrF[(lr*4 + j)*68 + w*16 + lc] = hv;                                  \
    }                                                                          \
    BAR();                                                                     \
    if (step < HALF_ - 1) {   /* producer store: one 8B dword-pair per thread */ \
        bf16x4 v = *reinterpret_cast<bf16x4*>(&htr[sb*68 + sg*4]);             \
        short* hn = hbuf + (size_t)(step & 1) * HBUF_HALF + hstore_off;        \
        asm volatile("global_store_dwordx2 %0, %1, off sc0 sc1"                \
                     :: "v"(hn), "v"(v) : "memory");                           \
    }                                                                          \
    {                                                                          \
        f32x4 ov = *reinterpret_cast<f32x4*>(&htrF[sb*68 + sg*4]);             \
        float* op_ = out + (size_t)(((g*16 + sb) * T_ + tt) * H_ + s*64 + sg*4); \
        asm volatile("global_store_dwordx4 %0, %1, off"                        \
                     :: "v"(op_), "v"(ov) : "memory");                         \
        if (p == 0 && step == HALF_ - 1) {                                     \
            float* fp_ = out + (size_t)B_*T_*H_ + (size_t)((g*16 + sb) * H_ + s*64 + sg*4); \
            asm volatile("global_store_dwordx4 %0, %1, off"                    \
                         :: "v"(fp_), "v"(ov) : "memory");                     \
        }                                                                      \
    }                                                                          \
}

__global__ __launch_bounds__(256, 1) void rnn_scan(
        const float* __restrict__ Whh, float* __restrict__ out,
        short* __restrict__ hbuf) {
    __shared__ short hB[16 * 1024];   // h stage [16 batch][1024 k], swizzled
    __shared__ short htr[16 * 68];    // fp16+epoch transpose [batch][col+pad]
    __shared__ float htrF[16 * 68];   // f32 transpose for coalesced out stores
    const int wg = blockIdx.x;
    const int p  = wg >> 6;           // parity
    const int g  = (wg >> 4) & 3;     // batch group (16 batches)
    const int s  = wg & 15;           // col slice (64 cols)
    const int tid = threadIdx.x;
    const int l  = tid & 63;
    const int w  = tid >> 6;
    const int lc = l & 15, lr = l >> 4;
    const int sb = tid >> 4;          // staging batch row 0..15
    const int sg = tid & 15;          // staging granule index

    // W_hh rows [s*64 + w*16 + lc], fp32 -> fp16, direct to 128 VGPRs
    bf16x8 breg[32];
    {
        const float* wrow = Whh + (size_t)(s*64 + w*16 + lc) * 1024;
#pragma unroll
        for (int kc = 0; kc < 32; kc++) {
            f32x4 v0 = *reinterpret_cast<const f32x4*>(wrow + kc*32 + lr*8);
            f32x4 v1 = *reinterpret_cast<const f32x4*>(wrow + kc*32 + lr*8 + 4);
            bf16x8 q = { f2h(v0.x), f2h(v0.y), f2h(v0.z), f2h(v0.w),
                         f2h(v1.x), f2h(v1.y), f2h(v1.z), f2h(v1.w) };
            breg[kc] = q;
        }
    }

    const unsigned hload_base = (unsigned)((p*64 + g*16 + sb) * 1024 + sg*8);
    const unsigned hstore_off = (unsigned)((p*64 + g*16 + sb) * 1024 + s*64 + sg*4);
    const int col = s*64 + w*16 + lc;

    bf16x8 hl[8];
    float giA[4], giB[4];

    // prologue: issue gi(0); step 0's vmcnt(0) drains it
    {
        const int t0 = (p == 0) ? 0 : T_ - 1;
#pragma unroll
        for (int j = 0; j < 4; j++) {
            const float* ga = out + (size_t)(((g*16 + lr*4 + j) * T_ + t0) * H_ + col);
            asm volatile("global_load_dword %0, %1, off"
                         : "=v"(giA[j]) : "v"(ga) : "memory");
        }
    }

    for (int sp = 0; sp < HALF_; sp += 2) {
        STEP_BODY(sp,     giA, giB)
        STEP_BODY(sp + 1, giB, giA)
    }
}

extern "C" void kernel_launch(void* const* d_in, const int* in_sizes, int n_in,
                              void* d_out, int out_size, void* d_ws, size_t ws_size,
                              hipStream_t stream) {
    const float* X   = (const float*)d_in[0];
    const float* Wih = (const float*)d_in[1];
    const float* Whh = (const float*)d_in[2];
    const float* bih = (const float*)d_in[3];
    const float* bhh = (const float*)d_in[4];
    float* out = (float*)d_out;

    short* hbuf = (short*)d_ws;   // [2 dbuf][2 p][64 b][1024] fp16 = 512 KB

    // Epoch 0 is invalid: zeroing hbuf rejects cross-graph-replay leftovers.
    hipMemsetAsync(hbuf, 0, (size_t)2 * HBUF_HALF * 2, stream);
    gi_gemm<<<dim3(4096), dim3(256), 0, stream>>>(X, Wih, bih, bhh, out);
    rnn_scan<<<dim3(NWG_SCAN), dim3(256), 0, stream>>>(Whh, out, hbuf);
}

// Round 7
// 1933.300 us; speedup vs baseline: 2.2514x; 1.1801x over previous
//
#include <hip/hip_runtime.h>

#define B_    64
#define T_    1024
#define H_    1024
#define HALF_ 512
#define NWG_SCAN 128
#define HBUF_HALF 131072   // shorts per double-buffer half: 2*64*1024

typedef short bf16x8 __attribute__((ext_vector_type(8)));
typedef short bf16x4 __attribute__((ext_vector_type(4)));
typedef _Float16 f16x8 __attribute__((ext_vector_type(8)));
typedef float f32x4  __attribute__((ext_vector_type(4)));
typedef unsigned int u32x4 __attribute__((ext_vector_type(4)));

__device__ __forceinline__ short f2bf(float f) {
    unsigned u = __builtin_bit_cast(unsigned, f);
    u += 0x7fffu + ((u >> 16) & 1u);
    return (short)(u >> 16);
}

__device__ __forceinline__ short f2h(float f) {
    return (short)__builtin_bit_cast(unsigned short, (_Float16)f);
}

__device__ __forceinline__ float tanh_fast(float x) {
    return 1.0f - 2.0f / (__expf(2.0f * x) + 1.0f);
}

// LDS-only barrier: hipcc's __syncthreads emits s_waitcnt vmcnt(0) before
// s_barrier, forcing every step to wait on the previous step's store
// retirement twice. This waits LDS ops only; vmem stays in flight.
#define BAR() do { \
    __builtin_amdgcn_sched_barrier(0); \
    asm volatile("s_waitcnt lgkmcnt(0)" ::: "memory"); \
    __builtin_amdgcn_sched_barrier(0); \
    __builtin_amdgcn_s_barrier(); \
    __builtin_amdgcn_sched_barrier(0); \
} while (0)

// ---------------- Phase 1: gi = bf16(x) @ bf16(W_ih)^T + (b_ih + b_hh) --------
__global__ __launch_bounds__(256) void gi_gemm(
        const float* __restrict__ X, const float* __restrict__ Wih,
        const float* __restrict__ bih, const float* __restrict__ bhh,
        float* __restrict__ out) {
    __shared__ short As[128][40];
    __shared__ short Bs[128][40];
    const int bid = blockIdx.x;
    const int tn = bid & 7;
    const int tm = bid >> 3;
    const int tid = threadIdx.x;
    const int l  = tid & 63;
    const int w  = tid >> 6;
    const int wr = w >> 1, wc = w & 1;
    const int lc = l & 15,  lr = l >> 4;

    const float* Ab = X   + (size_t)tm * 128 * 1024;
    const float* Bb = Wih + (size_t)tn * 128 * 1024;
    const int srow = tid >> 3;
    const int sc4  = (tid & 7) * 4;

    f32x4 acc[4][4];
#pragma unroll
    for (int m = 0; m < 4; m++)
#pragma unroll
        for (int n = 0; n < 4; n++) acc[m][n] = (f32x4){0.f, 0.f, 0.f, 0.f};

    f32x4 ra[4], rb[4];
#pragma unroll
    for (int c = 0; c < 4; c++) {
        ra[c] = *reinterpret_cast<const f32x4*>(Ab + (size_t)(srow + 32*c) * 1024 + sc4);
        rb[c] = *reinterpret_cast<const f32x4*>(Bb + (size_t)(srow + 32*c) * 1024 + sc4);
    }

    for (int k0 = 0; k0 < 1024; k0 += 32) {
        __syncthreads();
#pragma unroll
        for (int c = 0; c < 4; c++) {
            bf16x4 va = { f2bf(ra[c].x), f2bf(ra[c].y), f2bf(ra[c].z), f2bf(ra[c].w) };
            bf16x4 vb = { f2bf(rb[c].x), f2bf(rb[c].y), f2bf(rb[c].z), f2bf(rb[c].w) };
            *reinterpret_cast<bf16x4*>(&As[srow + 32*c][sc4]) = va;
            *reinterpret_cast<bf16x4*>(&Bs[srow + 32*c][sc4]) = vb;
        }
        __syncthreads();
        if (k0 + 32 < 1024) {
            const float* Ak = Ab + k0 + 32;
            const float* Bk = Bb + k0 + 32;
#pragma unroll
            for (int c = 0; c < 4; c++) {
                ra[c] = *reinterpret_cast<const f32x4*>(Ak + (size_t)(srow + 32*c) * 1024 + sc4);
                rb[c] = *reinterpret_cast<const f32x4*>(Bk + (size_t)(srow + 32*c) * 1024 + sc4);
            }
        }
        bf16x8 af[4], bfr[4];
#pragma unroll
        for (int m = 0; m < 4; m++)
            af[m] = *reinterpret_cast<bf16x8*>(&As[wr*64 + m*16 + lc][lr*8]);
#pragma unroll
        for (int n = 0; n < 4; n++)
            bfr[n] = *reinterpret_cast<bf16x8*>(&Bs[wc*64 + n*16 + lc][lr*8]);
#pragma unroll
        for (int m = 0; m < 4; m++)
#pragma unroll
            for (int n = 0; n < 4; n++)
                acc[m][n] = __builtin_amdgcn_mfma_f32_16x16x32_bf16(af[m], bfr[n], acc[m][n], 0, 0, 0);
    }

#pragma unroll
    for (int n = 0; n < 4; n++) {
        const int col = tn*128 + wc*64 + n*16 + lc;
        const float bs = bih[col] + bhh[col];
#pragma unroll
        for (int m = 0; m < 4; m++) {
            const int row0 = tm*128 + wr*64 + m*16 + lr*4;
#pragma unroll
            for (int j = 0; j < 4; j++)
                out[(size_t)(row0 + j) * 1024 + col] = acc[m][n][j] + bs;
        }
    }
}

// ---------------- Phase 2: batch-partitioned barrier-free scan ---------------
// EXACT Round-0 baseline structure (vmcnt(4) poll with gi in flight, epoch-LSB
// protocol, device-scope sc0 sc1 exchange) with exactly two changes:
//  (1) __syncthreads -> BAR(): removes the two per-step vmcnt(0) store-drains,
//  (2) out[] stores coalesced to one dwordx4/thread via f32 LDS transpose
//      (faster retirement; with BAR the prev stores sit ahead of the h loads
//      in the vmem FIFO, so the poll's vmcnt(4) inherits their retirement).
// Epoch = step%3+1 (0 invalid; hbuf zeroed per launch). Stale/unarrived
// register data fails the epoch check and is retried (vmcnt under-wait safe).
__global__ __launch_bounds__(256, 1) void rnn_scan(
        const float* __restrict__ Whh, float* __restrict__ out,
        short* __restrict__ hbuf) {
    __shared__ short hB[16 * 1024];   // h stage [16 batch][1024 k], swizzled
    __shared__ short htr[16 * 68];    // fp16+epoch transpose [batch][col+pad]
    __shared__ float htrF[16 * 68];   // f32 transpose for coalesced out stores
    const int wg = blockIdx.x;
    const int p  = wg >> 6;           // parity
    const int g  = (wg >> 4) & 3;     // batch group (16 batches)
    const int s  = wg & 15;           // col slice (64 cols)
    const int tid = threadIdx.x;
    const int l  = tid & 63;
    const int w  = tid >> 6;
    const int lc = l & 15, lr = l >> 4;
    const int sb = tid >> 4;          // staging batch row 0..15
    const int sg = tid & 15;          // staging granule index

    // W_hh rows [s*64 + w*16 + lc], fp32 -> fp16, direct to 128 VGPRs
    bf16x8 breg[32];
    {
        const float* wrow = Whh + (size_t)(s*64 + w*16 + lc) * 1024;
#pragma unroll
        for (int kc = 0; kc < 32; kc++) {
            f32x4 v0 = *reinterpret_cast<const f32x4*>(wrow + kc*32 + lr*8);
            f32x4 v1 = *reinterpret_cast<const f32x4*>(wrow + kc*32 + lr*8 + 4);
            bf16x8 q = { f2h(v0.x), f2h(v0.y), f2h(v0.z), f2h(v0.w),
                         f2h(v1.x), f2h(v1.y), f2h(v1.z), f2h(v1.w) };
            breg[kc] = q;
        }
    }

    const unsigned hload_base = (unsigned)((p*64 + g*16 + sb) * 1024 + sg*8);
    const unsigned hstore_off = (unsigned)((p*64 + g*16 + sb) * 1024 + s*64 + sg*4);
    const int col = s*64 + w*16 + lc;

    for (int step = 0; step < HALF_; step++) {
        const int tt = (p == 0) ? (2*step) : (step == 0 ? T_-1 : 2*step - 1);
        const int epw = step % 3 + 1;
        const int epv = (step + 2) % 3 + 1;   // prev step's epw
        f32x4 acc = (f32x4){0.f, 0.f, 0.f, 0.f};
        float gi[4]; unsigned ob[4];

        if (step) {
            // 8 x 16B loads of this group's h (contiguous 32 KB per WG)
            bf16x8 hl[8];
            const short* hc = hbuf + (size_t)((step+1) & 1) * HBUF_HALF + hload_base;
#pragma unroll
            for (int c = 0; c < 8; c++)
                asm volatile("global_load_dwordx4 %0, %1, off sc0 sc1"
                             : "=v"(hl[c]) : "v"(hc + c*128) : "memory");
            // gi loads (normal cached; overlap with h flight)
#pragma unroll
            for (int j = 0; j < 4; j++) {
                ob[j] = (unsigned)(((g*16 + lr*4 + j) * T_ + tt) * H_ + col);
                gi[j] = out[ob[j]];
            }
            const unsigned pat = (unsigned)((epv & 1) | (((epv >> 1) & 1) << 16));
            unsigned pend = 0;
            asm volatile("s_waitcnt vmcnt(4)" ::: "memory");   // h done, gi flying
            __builtin_amdgcn_sched_barrier(0);
#pragma unroll
            for (int c = 0; c < 8; c++) {
                u32x4 d = __builtin_bit_cast(u32x4, hl[c]);
                unsigned m = ((d[0] & 0x00010001u) ^ pat) | ((d[1] & 0x00010001u) ^ pat)
                           | ((d[2] & 0x00010001u) ^ pat) | ((d[3] & 0x00010001u) ^ pat);
                if (!__all(m == 0)) pend |= 1u << c;
            }
            while (pend) {   // retry stale slots until producer stores land
#pragma unroll
                for (int c = 0; c < 8; c++)
                    if (pend & (1u << c))
                        asm volatile("global_load_dwordx4 %0, %1, off sc0 sc1"
                                     : "=v"(hl[c]) : "v"(hc + c*128) : "memory");
                asm volatile("s_waitcnt vmcnt(0)" ::: "memory");
                __builtin_amdgcn_sched_barrier(0);
#pragma unroll
                for (int c = 0; c < 8; c++) {
                    if (pend & (1u << c)) {
                        u32x4 d = __builtin_bit_cast(u32x4, hl[c]);
                        unsigned m = ((d[0] & 0x00010001u) ^ pat) | ((d[1] & 0x00010001u) ^ pat)
                                   | ((d[2] & 0x00010001u) ^ pat) | ((d[3] & 0x00010001u) ^ pat);
                        if (__all(m == 0)) pend &= ~(1u << c);
                    }
                }
            }
            // stage to LDS, swizzled: granule g8 -> g8 ^ (row & 15)
#pragma unroll
            for (int c = 0; c < 8; c++) {
                bf16x4 lo = { hl[c][0], hl[c][1], hl[c][2], hl[c][3] };
                bf16x4 hi = { hl[c][4], hl[c][5], hl[c][6], hl[c][7] };
                const int g8 = (sg + c*16) * 2;
                *reinterpret_cast<bf16x4*>(&hB[sb*1024 + (((g8    ) ^ sb) << 2)]) = lo;
                *reinterpret_cast<bf16x4*>(&hB[sb*1024 + (((g8 + 1) ^ sb) << 2)]) = hi;
            }
            BAR();
            // fragment reads + MFMA (4 independent chains)
            f32x4 a0 = (f32x4){0,0,0,0}, a1 = (f32x4){0,0,0,0};
            f32x4 a2 = (f32x4){0,0,0,0}, a3 = (f32x4){0,0,0,0};
#pragma unroll
            for (int kc = 0; kc < 32; kc += 4) {
#pragma unroll
                for (int q = 0; q < 4; q++) {
                    const int k8 = (kc + q) * 8 + lr * 2;
                    bf16x4 lo = *reinterpret_cast<const bf16x4*>(&hB[lc*1024 + (((k8    ) ^ lc) << 2)]);
                    bf16x4 hi = *reinterpret_cast<const bf16x4*>(&hB[lc*1024 + (((k8 + 1) ^ lc) << 2)]);
                    bf16x8 hf = { lo[0], lo[1], lo[2], lo[3], hi[0], hi[1], hi[2], hi[3] };
                    f32x4& aq = (q == 0) ? a0 : (q == 1) ? a1 : (q == 2) ? a2 : a3;
                    aq = __builtin_amdgcn_mfma_f32_16x16x32_f16(
                        __builtin_bit_cast(f16x8, hf),
                        __builtin_bit_cast(f16x8, breg[kc + q]), aq, 0, 0, 0);
                }
            }
            acc = (a0 + a1) + (a2 + a3);
        } else {
#pragma unroll
            for (int j = 0; j < 4; j++) {
                ob[j] = (unsigned)(((g*16 + lr*4 + j) * T_ + tt) * H_ + col);
                gi[j] = out[ob[j]];
            }
        }

        // h = tanh(acc + gi); fp16 + epoch LSB; transposes via LDS
        const unsigned short ebit = (unsigned short)((lc & 1) ? ((epw >> 1) & 1) : (epw & 1));
#pragma unroll
        for (int j = 0; j < 4; j++) {
            float hv = tanh_fast(acc[j] + gi[j]);
            unsigned short u = __builtin_bit_cast(unsigned short, (_Float16)hv);
            u = (unsigned short)((u & 0xFFFEu) | ebit);
            htr [(lr*4 + j)*68 + w*16 + lc] = (short)u;
            htrF[(lr*4 + j)*68 + w*16 + lc] = hv;
        }
        BAR();   // htr/htrF ready AND all waves done with hB reads

        if (step < HALF_ - 1) {   // producer store: one 8B dword-pair per thread
            bf16x4 v = *reinterpret_cast<bf16x4*>(&htr[sb*68 + sg*4]);
            short* hn = hbuf + (size_t)(step & 1) * HBUF_HALF + hstore_off;
            asm volatile("global_store_dwordx2 %0, %1, off sc0 sc1"
                         :: "v"(hn), "v"(v) : "memory");
        }

        // coalesced out[] store: one dwordx4/thread, contiguous 256B rows
        {
            f32x4 ov = *reinterpret_cast<f32x4*>(&htrF[sb*68 + sg*4]);
            float* op_ = out + (size_t)(((g*16 + sb) * T_ + tt) * H_ + s*64 + sg*4);
            asm volatile("global_store_dwordx4 %0, %1, off"
                         :: "v"(op_), "v"(ov) : "memory");
            if (p == 0 && step == HALF_ - 1) {
                float* fp_ = out + (size_t)B_*T_*H_ + (size_t)((g*16 + sb) * H_ + s*64 + sg*4);
                asm volatile("global_store_dwordx4 %0, %1, off"
                             :: "v"(fp_), "v"(ov) : "memory");
            }
        }
    }
}

extern "C" void kernel_launch(void* const* d_in, const int* in_sizes, int n_in,
                              void* d_out, int out_size, void* d_ws, size_t ws_size,
                              hipStream_t stream) {
    const float* X   = (const float*)d_in[0];
    const float* Wih = (const float*)d_in[1];
    const float* Whh = (const float*)d_in[2];
    const float* bih = (const float*)d_in[3];
    const float* bhh = (const float*)d_in[4];
    float* out = (float*)d_out;

    short* hbuf = (short*)d_ws;   // [2 dbuf][2 p][64 b][1024] fp16 = 512 KB

    // Epoch 0 is invalid: zeroing hbuf rejects cross-graph-replay leftovers.
    hipMemsetAsync(hbuf, 0, (size_t)2 * HBUF_HALF * 2, stream);
    gi_gemm<<<dim3(4096), dim3(256), 0, stream>>>(X, Wih, bih, bhh, out);
    rnn_scan<<<dim3(NWG_SCAN), dim3(256), 0, stream>>>(Whh, out, hbuf);
}